// Round 1
// 1229.090 us; speedup vs baseline: 1.2386x; 1.2386x over previous
//
#include <hip/hip_runtime.h>
#include <stdint.h>

// ---------- types ----------
typedef __bf16 bf16x8 __attribute__((ext_vector_type(8)));
typedef float  f32x4  __attribute__((ext_vector_type(4)));
typedef unsigned short ushortx8 __attribute__((ext_vector_type(8)));
typedef unsigned short ushortx4 __attribute__((ext_vector_type(4)));

#define DEVI __device__ __forceinline__

DEVI unsigned short f2bf(float f) {
  union { float f; unsigned int u; } v; v.f = f;
  unsigned int r = v.u + 0x7fffu + ((v.u >> 16) & 1u);
  return (unsigned short)(r >> 16);
}
DEVI float bf2f(unsigned short h) {
  union { unsigned int u; float f; } v; v.u = ((unsigned int)h) << 16;
  return v.f;
}

// async global->LDS, 16B per lane
DEVI void gl_lds16(const unsigned short* g, unsigned short* l) {
  __builtin_amdgcn_global_load_lds(
      (__attribute__((address_space(1))) unsigned int*)g,
      (__attribute__((address_space(3))) unsigned int*)l,
      16, 0, 0);
}

// raw barrier WITHOUT the __syncthreads fence (no forced vmcnt(0) drain).
DEVI void raw_barrier() {
  asm volatile("" ::: "memory");
  __builtin_amdgcn_s_barrier();
  asm volatile("" ::: "memory");
}
// s_waitcnt imm: vmcnt[3:0]|[15:14], expcnt[6:4], lgkmcnt[11:8]
#define WAITCNT_VM4    0x0F74  // vmcnt<=4, exp/lgkm unconstrained
#define WAITCNT_VM0    0x0F70  // vmcnt=0
#define WAITCNT_LGKM0  0xC07F  // lgkmcnt=0, vm/exp unconstrained

DEVI void store_out(float* p, float v) { *p = v; }
DEVI void store_out(unsigned short* p, float v) { *p = f2bf(v); }

// ---------- GroupNorm stats: one block per (batch, group) ----------
__global__ __launch_bounds__(256) void gn_stats(const float* __restrict__ x,
                                                float* __restrict__ stats) {
  const int bg = blockIdx.x;
  const float* p = x + (size_t)bg * 65536;
  const int tid = threadIdx.x;
  float s = 0.f, ss = 0.f;
#pragma unroll 4
  for (int i = 0; i < 64; ++i) {
    float4 v = *(const float4*)(p + (((size_t)i * 256 + tid) << 2));
    s  += v.x + v.y + v.z + v.w;
    ss += v.x * v.x + v.y * v.y + v.z * v.z + v.w * v.w;
  }
  for (int off = 32; off; off >>= 1) { s += __shfl_xor(s, off); ss += __shfl_xor(ss, off); }
  __shared__ float rs[4], rss[4];
  const int lane = tid & 63, wave = tid >> 6;
  if (lane == 0) { rs[wave] = s; rss[wave] = ss; }
  __syncthreads();
  if (tid == 0) {
    float S1 = rs[0] + rs[1] + rs[2] + rs[3];
    float S2 = rss[0] + rss[1] + rss[2] + rss[3];
    float mean = S1 * (1.f / 65536.f);
    float var  = S2 * (1.f / 65536.f) - mean * mean;
    stats[bg * 2 + 0] = mean;
    stats[bg * 2 + 1] = rsqrtf(var + 1e-5f);
  }
}

// ---------- GN apply + transpose to token-major bf16 h_t[B,4096,512] ----------
__global__ __launch_bounds__(256) void gn_apply(const float* __restrict__ x,
                                                const float* __restrict__ stats,
                                                const float* __restrict__ gamma,
                                                const float* __restrict__ beta,
                                                unsigned short* __restrict__ h_t) {
  __shared__ alignas(16) unsigned short tile[64 * 136];
  const int tid = threadIdx.x;
  const int t0 = blockIdx.x * 64;
  const int c0 = blockIdx.y * 128;
  const int b  = blockIdx.z;
  const float* xb = x + ((size_t)b * 512 + c0) * 4096 + t0;
#pragma unroll
  for (int j = 0; j < 8; ++j) {
    int f = tid + j * 256;
    int r = f >> 4;
    int tc = (f & 15) << 2;
    float4 v = *(const float4*)(xb + (size_t)r * 4096 + tc);
    int ch = c0 + r;
    int g = ch >> 4;
    float mean = stats[((size_t)b * 32 + g) * 2 + 0];
    float rstd = stats[((size_t)b * 32 + g) * 2 + 1];
    float ga = gamma[ch] * rstd;
    float be = beta[ch] - mean * ga;
    tile[(tc + 0) * 136 + r] = f2bf(v.x * ga + be);
    tile[(tc + 1) * 136 + r] = f2bf(v.y * ga + be);
    tile[(tc + 2) * 136 + r] = f2bf(v.z * ga + be);
    tile[(tc + 3) * 136 + r] = f2bf(v.w * ga + be);
  }
  __syncthreads();
  unsigned short* hb = h_t + (size_t)b * 4096 * 512;
#pragma unroll
  for (int j = 0; j < 4; ++j) {
    int f = tid + j * 256;
    int tok = f >> 4;
    int cc = (f & 15) << 3;
    ushortx8 v = *(const ushortx8*)&tile[tok * 136 + cc];
    *(ushortx8*)(hb + (size_t)(t0 + tok) * 512 + c0 + cc) = v;
  }
}

// ---------- fp32 -> bf16 weight convert ----------
__global__ __launch_bounds__(256) void cvt_f32_bf16(const float* __restrict__ s,
                                                    unsigned short* __restrict__ d) {
  int i = (blockIdx.x * 256 + threadIdx.x) * 4;
  float4 v = *(const float4*)(s + i);
  ushortx4 o;
  o[0] = f2bf(v.x); o[1] = f2bf(v.y); o[2] = f2bf(v.z); o[3] = f2bf(v.w);
  *(ushortx4*)(d + i) = o;
}

// ---------- 256x256 8-phase NT-form MFMA GEMM (T2+T3+T4+T5) ----------
// D[m,n] = alpha * sum_k A[m,k]*B[n,k] (+bias)(+resid)
// 512 threads = 8 waves (2M x 4N); per wave 128x64 output.
// LDS: slot0 {A,B} + slot1 {A,B}, 32KB each = 128KB. Slot s holds K-tile parity s.
// K-slot XOR swizzle (slot ^= row&7) applied on BOTH sides: pre-swizzled global
// source for global_load_lds (LDS dest stays linear), swizzled ds_read address.
template <int BIAS_MODE, int RESID, typename OT>
__global__ __launch_bounds__(512, 2) void gemm_nt_256(
    const unsigned short* __restrict__ A, const unsigned short* __restrict__ B,
    OT* __restrict__ D, const float* __restrict__ bias,
    const float* __restrict__ resid, int M, int N, int K,
    long long sA, long long sB, long long sD, long long sR, float alpha) {
  __shared__ alignas(128) char sm[131072];
  char* const sA0 = sm;
  char* const sB0 = sm + 32768;
  char* const sA1 = sm + 65536;
  char* const sB1 = sm + 98304;

  const int tid = threadIdx.x;
  const int bz = blockIdx.x, bn = blockIdx.y, bm = blockIdx.z;
  const unsigned short* Ab = A + (size_t)bz * sA + (size_t)bm * 256 * K;
  const unsigned short* Bb = B + (size_t)bz * sB + (size_t)bn * 256 * K;

  const int lane = tid & 63;
  const int ln = lane & 15, quad = lane >> 4;
  const int wave = tid >> 6;
  const int wm = wave >> 2, wn = wave & 3;

  // staging geometry: thread t stages 16B; half-tile = 128 rows x 64k = 2 loads.
  // linear LDS off (j*8192 + t*16) -> row = j*64 + (t>>3), lds k-slot = t&7;
  // source k-slot = (t&7) ^ (row&7)   (row&7 == (t>>3)&7 since 64%8==0)
  const int prow = tid >> 3;
  const unsigned ks = (unsigned)((tid & 7) ^ (prow & 7));
  const unsigned srcoff = (unsigned)prow * (unsigned)K + ks * 8u;  // elements
  const unsigned ldst = (unsigned)tid * 16u;                       // bytes

  // compute-read geometry (byte offsets into a 256x64 tile, row stride 128B)
  const int aro = (wm * 128 + ln) * 128;   // + mf*2048
  const int bro = (wn * 64 + ln) * 128;    // + nf*2048
  const int sl0 = ((quad ^ (ln & 7)) << 4);        // k-step 0, swizzled slot
  const int sl1 = (((4 + quad) ^ (ln & 7)) << 4);  // k-step 1

  f32x4 acc[8][4] = {};
  bf16x8 a0[8], a1[8], b0[4], b1[4];

#define STAGE(G, SMp, h, ktv) do {                                                   \
    const unsigned short* _g = (G) + (unsigned)(h) * 128u * (unsigned)K +            \
                               (unsigned)(ktv) * 64u + srcoff;                       \
    gl_lds16(_g, (unsigned short*)((SMp) + (h) * 16384 + ldst));                     \
    gl_lds16(_g + (size_t)64 * K, (unsigned short*)((SMp) + (h) * 16384 + 8192 + ldst)); \
  } while (0)

#define RD_A(SMp, SL, dst) do { _Pragma("unroll")                                    \
    for (int _mf = 0; _mf < 8; ++_mf)                                                \
      dst[_mf] = *(const bf16x8*)((SMp) + aro + _mf * 2048 + (SL)); } while (0)
#define RD_B(SMp, SL, dst) do { _Pragma("unroll")                                    \
    for (int _nf = 0; _nf < 4; ++_nf)                                                \
      dst[_nf] = *(const bf16x8*)((SMp) + bro + _nf * 2048 + (SL)); } while (0)

#define MM(AF, BF, N0) do {                                                          \
    __builtin_amdgcn_s_setprio(1);                                                   \
    _Pragma("unroll")                                                                \
    for (int _mf = 0; _mf < 8; ++_mf) {                                              \
      acc[_mf][(N0)]     = __builtin_amdgcn_mfma_f32_16x16x32_bf16(AF[_mf], BF[(N0)],     acc[_mf][(N0)],     0, 0, 0); \
      acc[_mf][(N0) + 1] = __builtin_amdgcn_mfma_f32_16x16x32_bf16(AF[_mf], BF[(N0) + 1], acc[_mf][(N0) + 1], 0, 0, 0); \
    }                                                                                \
    __builtin_amdgcn_s_setprio(0);                                                   \
  } while (0)

  // prologue: kt0 fully + kt1 A-halves (kt1 B-halves come at P0/P1 of iter 0)
  STAGE(Ab, sA0, 0, 0); STAGE(Ab, sA0, 1, 0);
  STAGE(Bb, sB0, 0, 0); STAGE(Bb, sB0, 1, 0);
  STAGE(Ab, sA1, 0, 1); STAGE(Ab, sA1, 1, 1);
  __builtin_amdgcn_s_waitcnt(WAITCNT_VM4);  // kt0's 8 loads done (kt1.A in flight)
  raw_barrier();

  const int NI = K >> 7;  // number of 2-K-tile iterations
  int kt0 = 0;
  for (int i = 0; i < NI - 1; ++i, kt0 += 2) {
    // P0: slot0 kk0, n-frags 0-1
    RD_A(sA0, sl0, a0); RD_B(sB0, sl0, b0);
    STAGE(Bb, sB1, 0, kt0 + 1);
    raw_barrier();
    MM(a0, b0, 0);
    raw_barrier();
    // P1: slot0 kk0, n-frags 2-3 (reads kk1 frags for P2/P3)
    RD_A(sA0, sl1, a1); RD_B(sB0, sl1, b1);
    STAGE(Bb, sB1, 1, kt0 + 1);
    raw_barrier();
    MM(a0, b0, 2);
    __builtin_amdgcn_s_waitcnt(WAITCNT_LGKM0);  // all slot0 reads in regs -> restage ok
    raw_barrier();
    // P2
    STAGE(Ab, sA0, 0, kt0 + 2);
    raw_barrier();
    MM(a1, b1, 0);
    raw_barrier();
    // P3  (vmcnt(4): kt0+1 fully landed; kt0+2 A-halves may fly)
    STAGE(Ab, sA0, 1, kt0 + 2);
    raw_barrier();
    MM(a1, b1, 2);
    __builtin_amdgcn_s_waitcnt(WAITCNT_VM4);
    raw_barrier();
    // P4: slot1 kk0, n 0-1
    RD_A(sA1, sl0, a0); RD_B(sB1, sl0, b0);
    STAGE(Bb, sB0, 0, kt0 + 2);
    raw_barrier();
    MM(a0, b0, 0);
    raw_barrier();
    // P5
    RD_A(sA1, sl1, a1); RD_B(sB1, sl1, b1);
    STAGE(Bb, sB0, 1, kt0 + 2);
    raw_barrier();
    MM(a0, b0, 2);
    __builtin_amdgcn_s_waitcnt(WAITCNT_LGKM0);  // slot1 reads drained -> restage ok
    raw_barrier();
    // P6
    STAGE(Ab, sA1, 0, kt0 + 3);
    raw_barrier();
    MM(a1, b1, 0);
    raw_barrier();
    // P7  (vmcnt(4): kt0+2 fully landed; kt0+3 A-halves may fly)
    STAGE(Ab, sA1, 1, kt0 + 3);
    raw_barrier();
    MM(a1, b1, 2);
    __builtin_amdgcn_s_waitcnt(WAITCNT_VM4);
    raw_barrier();
  }
  // last iteration: stage only the final K-tile's B halves; drain before slot1 use
  {
    RD_A(sA0, sl0, a0); RD_B(sB0, sl0, b0);
    STAGE(Bb, sB1, 0, kt0 + 1);
    raw_barrier();
    MM(a0, b0, 0);
    raw_barrier();
    RD_A(sA0, sl1, a1); RD_B(sB0, sl1, b1);
    STAGE(Bb, sB1, 1, kt0 + 1);
    raw_barrier();
    MM(a0, b0, 2);
    raw_barrier();
    raw_barrier();
    MM(a1, b1, 0);
    raw_barrier();
    raw_barrier();
    MM(a1, b1, 2);
    __builtin_amdgcn_s_waitcnt(WAITCNT_VM0);  // final B halves landed
    raw_barrier();
    RD_A(sA1, sl0, a0); RD_B(sB1, sl0, b0);
    raw_barrier();
    MM(a0, b0, 0);
    raw_barrier();
    RD_A(sA1, sl1, a1); RD_B(sB1, sl1, b1);
    raw_barrier();
    MM(a0, b0, 2);
    raw_barrier();
    MM(a1, b1, 0);
    MM(a1, b1, 2);
  }
#undef STAGE
#undef RD_A
#undef RD_B
#undef MM

  OT* Db = D + (size_t)bz * sD;
  const float* Rb = RESID ? (resid + (size_t)bz * sR) : nullptr;
#pragma unroll
  for (int mf = 0; mf < 8; ++mf) {
#pragma unroll
    for (int nf = 0; nf < 4; ++nf) {
#pragma unroll
      for (int r = 0; r < 4; ++r) {
        int row = bm * 256 + wm * 128 + mf * 16 + quad * 4 + r;
        int col = bn * 256 + wn * 64 + nf * 16 + ln;
        float v = acc[mf][nf][r] * alpha;
        if (BIAS_MODE == 1) v += bias[row];
        if (BIAS_MODE == 2) v += bias[col];
        size_t idx = (size_t)row * N + col;
        if (RESID) v += Rb[idx];
        store_out(&Db[idx], v);
      }
    }
  }
}

// ---------- row softmax over 4096 bf16, in place ----------
__global__ __launch_bounds__(256) void softmax_rows(unsigned short* __restrict__ S) {
  const int tid = threadIdx.x;
  unsigned short* p = S + (size_t)blockIdx.x * 4096 + tid * 16;
  ushortx8 u0 = *(const ushortx8*)p;
  ushortx8 u1 = *(const ushortx8*)(p + 8);
  float v[16];
#pragma unroll
  for (int i = 0; i < 8; ++i) { v[i] = bf2f(u0[i]); v[i + 8] = bf2f(u1[i]); }
  float m = v[0];
#pragma unroll
  for (int i = 1; i < 16; ++i) m = fmaxf(m, v[i]);
  for (int off = 32; off; off >>= 1) m = fmaxf(m, __shfl_xor(m, off));
  __shared__ float red[4];
  __shared__ float red2[4];
  const int lane = tid & 63, wave = tid >> 6;
  if (lane == 0) red[wave] = m;
  __syncthreads();
  m = fmaxf(fmaxf(red[0], red[1]), fmaxf(red[2], red[3]));
  float s = 0.f;
#pragma unroll
  for (int i = 0; i < 16; ++i) { v[i] = __expf(v[i] - m); s += v[i]; }
  for (int off = 32; off; off >>= 1) s += __shfl_xor(s, off);
  if (lane == 0) red2[wave] = s;
  __syncthreads();
  s = red2[0] + red2[1] + red2[2] + red2[3];
  float inv = 1.f / s;
#pragma unroll
  for (int i = 0; i < 8; ++i) { u0[i] = f2bf(v[i] * inv); u1[i] = f2bf(v[i + 8] * inv); }
  *(ushortx8*)p = u0;
  *(ushortx8*)(p + 8) = u1;
}

// ---------- host ----------
extern "C" void kernel_launch(void* const* d_in, const int* in_sizes, int n_in,
                              void* d_out, int out_size, void* d_ws, size_t ws_size,
                              hipStream_t stream) {
  const float* x   = (const float*)d_in[0];
  const float* gnw = (const float*)d_in[1];
  const float* gnb = (const float*)d_in[2];
  const float* wq  = (const float*)d_in[3];
  const float* bq  = (const float*)d_in[4];
  const float* wk  = (const float*)d_in[5];
  const float* bk  = (const float*)d_in[6];
  const float* wv  = (const float*)d_in[7];
  const float* bv  = (const float*)d_in[8];
  const float* wo  = (const float*)d_in[9];
  const float* bo  = (const float*)d_in[10];
  float* out = (float*)d_out;

  const size_t EB = 2097152;  // elems per batch in a [4096,512] buffer

  char* base = (char*)d_ws;
  unsigned short* h_t  = (unsigned short*)base;                    // 67,108,864 B
  unsigned short* wqb  = (unsigned short*)(base + 67108864);
  unsigned short* wkb  = wqb + 262144;
  unsigned short* wvb  = wkb + 262144;
  unsigned short* wob  = wvb + 262144;
  float*          stats = (float*)(base + 69206016);
  char*           dyn   = base + 69210112;
  size_t rem = ws_size > 69210112 ? ws_size - 69210112 : 0;

  // per-batch dynamic bytes: q+k+v (3 x 4 MiB) + S (32 MiB)
  int nb = 1;
  if      (rem >= (size_t)16 * 46137344) nb = 16;
  else if (rem >= (size_t)8  * 46137344) nb = 8;
  else if (rem >= (size_t)4  * 46137344) nb = 4;
  else if (rem >= (size_t)2  * 46137344) nb = 2;

  unsigned short* q  = (unsigned short*)dyn;
  unsigned short* kb = q  + (size_t)nb * EB;
  unsigned short* vb = kb + (size_t)nb * EB;
  unsigned short* Sb = (unsigned short*)(dyn + (size_t)nb * 3 * 4194304);
  unsigned short* attn = q;  // alias: q dead after S-GEMM within a chunk

  gn_stats<<<512, 256, 0, stream>>>(x, stats);
  gn_apply<<<dim3(64, 4, 16), 256, 0, stream>>>(x, stats, gnw, gnb, h_t);
  cvt_f32_bf16<<<256, 256, 0, stream>>>(wq, wqb);
  cvt_f32_bf16<<<256, 256, 0, stream>>>(wk, wkb);
  cvt_f32_bf16<<<256, 256, 0, stream>>>(wv, wvb);
  cvt_f32_bf16<<<256, 256, 0, stream>>>(wo, wob);

  const float sm_scale = 0.044194173824159216f;  // 1/sqrt(512)

  for (int b0 = 0; b0 < 16; b0 += nb) {
    const unsigned short* hc = h_t + (size_t)b0 * EB;
    // Q = h_t x wq^T  -> [tok, o] token-major   (grid: batch, bn, bm)
    gemm_nt_256<2, 0, unsigned short><<<dim3(nb, 2, 16), 512, 0, stream>>>(
        hc, wqb, q, bq, nullptr, 4096, 512, 512, (long long)EB, 0, (long long)EB, 0, 1.f);
    gemm_nt_256<2, 0, unsigned short><<<dim3(nb, 2, 16), 512, 0, stream>>>(
        hc, wkb, kb, bk, nullptr, 4096, 512, 512, (long long)EB, 0, (long long)EB, 0, 1.f);
    // V = wv x h_t^T -> [o, tok] channel-major
    gemm_nt_256<1, 0, unsigned short><<<dim3(nb, 16, 2), 512, 0, stream>>>(
        wvb, hc, vb, bv, nullptr, 512, 4096, 512, 0, (long long)EB, (long long)EB, 0, 1.f);
    // S = Q K^T * scale  [4096, 4096]
    gemm_nt_256<0, 0, unsigned short><<<dim3(nb, 16, 16), 512, 0, stream>>>(
        q, kb, Sb, nullptr, nullptr, 4096, 4096, 512,
        (long long)EB, (long long)EB, 16777216LL, 0, sm_scale);
    softmax_rows<<<nb * 4096, 256, 0, stream>>>(Sb);
    // attn = P x V^T -> [tok, c] token-major (writes over q region)
    gemm_nt_256<0, 0, unsigned short><<<dim3(nb, 2, 16), 512, 0, stream>>>(
        Sb, vb, attn, nullptr, nullptr, 4096, 512, 4096,
        16777216LL, (long long)EB, (long long)EB, 0, 1.f);
    // out = wo x attn^T + bo + x  [o, tok] fp32
    gemm_nt_256<1, 1, float><<<dim3(nb, 16, 2), 512, 0, stream>>>(
        wob, attn, out + (size_t)b0 * EB, bo, x + (size_t)b0 * EB,
        512, 4096, 512, 0, (long long)EB, (long long)EB, (long long)EB, 1.f);
  }
}